// Round 1
// baseline (1916.031 us; speedup 1.0000x reference)
//
#include <hip/hip_runtime.h>
#include <hip/hip_bf16.h>
#include <math.h>

#define NG 4096
#define HID 256

// ---------------- dtype detector: is batch_indices int32 (stride 1) or int64 (stride 2)?
// int64 little-endian view as int32 gives (v,0,v,0,...) -> sortedness violated once v>0.
__global__ void detect_kernel(const int* __restrict__ idx32, int* __restrict__ flag) {
  __shared__ int s;
  int t = threadIdx.x;
  if (t == 0) s = 0;
  __syncthreads();
  int dec = 0;
  for (int i = t; i < 4095; i += 256)
    if (idx32[i + 1] < idx32[i]) dec = 1;
  if (dec) atomicOr(&s, 1);
  __syncthreads();
  if (t == 0) *flag = s ? 2 : 1;
}

// ---------------- segment starts from sorted indices: starts[g] = first node with idx >= g
__global__ void bounds_kernel(const int* __restrict__ idx32, const int* __restrict__ flag,
                              int* __restrict__ starts, int n) {
  int st = *flag;
  int i = blockIdx.x * blockDim.x + threadIdx.x;
  if (i >= n) return;
  int cur = idx32[(size_t)i * st];
  int prev = (i == 0) ? -1 : idx32[(size_t)(i - 1) * st];
  if (cur != prev)
    for (int g = prev + 1; g <= cur; ++g) starts[g] = i;
  if (i == n - 1)
    for (int g = cur + 1; g <= NG; ++g) starts[g] = n;
}

// ---------------- fold W_hh into W_ih h-columns; combine biases
__global__ void prep_kernel(const float* __restrict__ W_ih, const float* __restrict__ W_hh,
                            const float* __restrict__ b_ih, const float* __restrict__ b_hh,
                            float* __restrict__ Wcat, float* __restrict__ bcat) {
  int i = blockIdx.x * blockDim.x + threadIdx.x;  // over 1024*512
  int j = i >> 9, k = i & 511;
  float w = W_ih[i];
  if (k < 256) w += W_hh[j * 256 + k];
  Wcat[i] = w;
  if (i < 1024) bcat[i] = b_ih[i] + b_hh[i];
}

// ---------------- zero h (x[:, :256] interleaved as rows of 512) and c; also zero r half
__global__ void init_kernel(float* __restrict__ x, float* __restrict__ c) {
  int i = blockIdx.x * blockDim.x + threadIdx.x;  // NG*512 threads
  x[i] = 0.f;
  if (i < NG * HID) c[i] = 0.f;
}

// ---------------- fused attention: one block per graph, online softmax, single pass over nodes
__global__ __launch_bounds__(256) void attn_kernel(const float* __restrict__ emb,
                                                   const int* __restrict__ starts,
                                                   float* __restrict__ x) {
  int g = blockIdx.x;
  int s = starts[g], e = starts[g + 1];
  int tid = threadIdx.x;
  if (s >= e) { x[(size_t)g * 512 + 256 + tid] = 0.f; return; }
  __shared__ float hs[256];
  __shared__ float redM[4], redS[4];
  __shared__ float redR[4][256];
  hs[tid] = x[(size_t)g * 512 + tid];
  __syncthreads();
  int wave = tid >> 6, lane = tid & 63;
  float4 h4 = *(const float4*)&hs[lane * 4];
  float M = -INFINITY, S = 0.f;
  float4 R = make_float4(0.f, 0.f, 0.f, 0.f);
  for (int n = s + wave; n < e; n += 4) {
    float4 v = *(const float4*)(emb + (size_t)n * 256 + lane * 4);
    float d = v.x * h4.x + v.y * h4.y + v.z * h4.z + v.w * h4.w;
#pragma unroll
    for (int off = 32; off > 0; off >>= 1) d += __shfl_xor(d, off, 64);
    if (d <= M) {               // wave-uniform branch (d same on all lanes)
      float w = __expf(d - M);
      S += w;
      R.x += w * v.x; R.y += w * v.y; R.z += w * v.z; R.w += w * v.w;
    } else {
      float cc = __expf(M - d); // 0 when M == -inf
      S = S * cc + 1.f;
      R.x = R.x * cc + v.x; R.y = R.y * cc + v.y; R.z = R.z * cc + v.z; R.w = R.w * cc + v.w;
      M = d;
    }
  }
  if (lane == 0) { redM[wave] = M; redS[wave] = S; }
  *(float4*)&redR[wave][lane * 4] = R;
  __syncthreads();
  float m = fmaxf(fmaxf(redM[0], redM[1]), fmaxf(redM[2], redM[3]));
  float St = 0.f, Rt = 0.f;
#pragma unroll
  for (int w = 0; w < 4; ++w) {
    float mw = redM[w];
    float f = (mw == -INFINITY) ? 0.f : __expf(mw - m);
    St += f * redS[w];
    Rt += f * redR[w][tid];
  }
  x[(size_t)g * 512 + 256 + tid] = Rt / St;
}

// ---------------- fp32 tiled GEMM: C(MxN) = A(MxK) @ B(NxK)^T + bias, optional ReLU
// 128x128 block tile, BK=8, 256 threads, 8x8 microtile split as 2x2 of 4x4.
#define GBM 128
#define GBN 128
#define GBK 8
__global__ __launch_bounds__(256) void gemm_nt_kernel(
    const float* __restrict__ A, const float* __restrict__ B,
    const float* __restrict__ bias, float* __restrict__ C,
    int M, int N, int K, int lda, int ldb, int ldc, int act) {
  __shared__ float As[GBK][GBM + 4];
  __shared__ float Bs[GBK][GBN + 4];
  int bm = blockIdx.y, bn = blockIdx.x;
  int tid = threadIdx.x;
  int tr = tid >> 4, tc = tid & 15;
  float acc[2][2][4][4] = {};
  int r0 = bm * GBM, c0 = bn * GBN;
  int lrow = tid >> 1, lk = (tid & 1) * 4;
  const float* Aptr = A + (size_t)(r0 + lrow) * lda + lk;
  const float* Bptr = B + (size_t)(c0 + lrow) * ldb + lk;
  for (int k0 = 0; k0 < K; k0 += GBK) {
    float4 va = *(const float4*)(Aptr + k0);
    float4 vb = *(const float4*)(Bptr + k0);
    As[lk + 0][lrow] = va.x; As[lk + 1][lrow] = va.y;
    As[lk + 2][lrow] = va.z; As[lk + 3][lrow] = va.w;
    Bs[lk + 0][lrow] = vb.x; Bs[lk + 1][lrow] = vb.y;
    Bs[lk + 2][lrow] = vb.z; Bs[lk + 3][lrow] = vb.w;
    __syncthreads();
#pragma unroll
    for (int k = 0; k < GBK; ++k) {
      float4 a0 = *(const float4*)&As[k][tr * 4];
      float4 a1 = *(const float4*)&As[k][64 + tr * 4];
      float4 b0 = *(const float4*)&Bs[k][tc * 4];
      float4 b1 = *(const float4*)&Bs[k][64 + tc * 4];
      float av[2][4] = {{a0.x, a0.y, a0.z, a0.w}, {a1.x, a1.y, a1.z, a1.w}};
      float bv[2][4] = {{b0.x, b0.y, b0.z, b0.w}, {b1.x, b1.y, b1.z, b1.w}};
#pragma unroll
      for (int rh = 0; rh < 2; ++rh)
#pragma unroll
        for (int ch = 0; ch < 2; ++ch)
#pragma unroll
          for (int i = 0; i < 4; ++i)
#pragma unroll
            for (int j = 0; j < 4; ++j)
              acc[rh][ch][i][j] += av[rh][i] * bv[ch][j];
    }
    __syncthreads();
  }
#pragma unroll
  for (int rh = 0; rh < 2; ++rh)
#pragma unroll
    for (int ch = 0; ch < 2; ++ch)
#pragma unroll
      for (int i = 0; i < 4; ++i) {
        int row = r0 + rh * 64 + tr * 4 + i;
        int col = c0 + ch * 64 + tc * 4;
        float4 o;
        o.x = acc[rh][ch][i][0] + bias[col + 0];
        o.y = acc[rh][ch][i][1] + bias[col + 1];
        o.z = acc[rh][ch][i][2] + bias[col + 2];
        o.w = acc[rh][ch][i][3] + bias[col + 3];
        if (act == 1) {
          o.x = fmaxf(o.x, 0.f); o.y = fmaxf(o.y, 0.f);
          o.z = fmaxf(o.z, 0.f); o.w = fmaxf(o.w, 0.f);
        }
        *(float4*)&C[(size_t)row * ldc + col] = o;
      }
}

// ---------------- LSTM elementwise: gates (G,1024) order i,f,g,o
__global__ __launch_bounds__(256) void lstm_kernel(const float* __restrict__ gates,
                                                   float* __restrict__ c,
                                                   float* __restrict__ x) {
  int g = blockIdx.x, j = threadIdx.x;
  const float* gr = gates + (size_t)g * 1024;
  float gi = gr[j], gf = gr[j + 256], gg = gr[j + 512], go = gr[j + 768];
  float si = 1.f / (1.f + __expf(-gi));
  float sf = 1.f / (1.f + __expf(-gf));
  float so = 1.f / (1.f + __expf(-go));
  float tg = tanhf(gg);
  float cn = sf * c[(size_t)g * 256 + j] + si * tg;
  c[(size_t)g * 256 + j] = cn;
  x[(size_t)g * 512 + j] = so * tanhf(cn);
}

extern "C" void kernel_launch(void* const* d_in, const int* in_sizes, int n_in,
                              void* d_out, int out_size, void* d_ws, size_t ws_size,
                              hipStream_t stream) {
  const float* emb   = (const float*)d_in[0];
  const int*   idx32 = (const int*)d_in[1];
  const float* W_ih  = (const float*)d_in[2];
  const float* W_hh  = (const float*)d_in[3];
  const float* b_ih  = (const float*)d_in[4];
  const float* b_hh  = (const float*)d_in[5];
  const float* W1    = (const float*)d_in[6];
  const float* b1    = (const float*)d_in[7];
  const float* W2    = (const float*)d_in[8];
  const float* b2    = (const float*)d_in[9];
  float* out = (float*)d_out;
  int N = in_sizes[1];

  char* ws = (char*)d_ws;
  size_t o = 0;
  int* flag     = (int*)(ws + o); o += 256;
  int* starts   = (int*)(ws + o); o += ((size_t)NG + 1) * 4; o = (o + 255) & ~(size_t)255;
  float* Wcat   = (float*)(ws + o); o += (size_t)1024 * 512 * 4;
  float* bcat   = (float*)(ws + o); o += 1024 * 4; o = (o + 255) & ~(size_t)255;
  float* x      = (float*)(ws + o); o += (size_t)NG * 512 * 4;
  float* c      = (float*)(ws + o); o += (size_t)NG * 256 * 4;
  float* gates  = (float*)(ws + o); o += (size_t)NG * 1024 * 4;
  float* hdn    = (float*)(ws + o); o += (size_t)NG * 256 * 4;

  detect_kernel<<<1, 256, 0, stream>>>(idx32, flag);
  bounds_kernel<<<(N + 255) / 256, 256, 0, stream>>>(idx32, flag, starts, N);
  prep_kernel<<<(1024 * 512) / 256, 256, 0, stream>>>(W_ih, W_hh, b_ih, b_hh, Wcat, bcat);
  init_kernel<<<(NG * 512) / 256, 256, 0, stream>>>(x, c);

  for (int step = 0; step < 6; ++step) {
    attn_kernel<<<NG, 256, 0, stream>>>(emb, starts, x);
    gemm_nt_kernel<<<dim3(1024 / GBN, 4096 / GBM), 256, 0, stream>>>(
        x, Wcat, bcat, gates, 4096, 1024, 512, 512, 512, 1024, 0);
    lstm_kernel<<<NG, 256, 0, stream>>>(gates, c, x);
  }

  gemm_nt_kernel<<<dim3(256 / GBN, 4096 / GBM), 256, 0, stream>>>(
      x, W1, b1, hdn, 4096, 256, 512, 512, 512, 256, 1);
  gemm_nt_kernel<<<dim3(256 / GBN, 4096 / GBM), 256, 0, stream>>>(
      hdn, W2, b2, out, 4096, 256, 256, 256, 256, 256, 0);
}

// Round 2
// 1540.183 us; speedup vs baseline: 1.2440x; 1.2440x over previous
//
#include <hip/hip_runtime.h>
#include <hip/hip_bf16.h>
#include <math.h>

#define NG 4096

typedef short bfrag __attribute__((ext_vector_type(8)));
typedef float f32x4 __attribute__((ext_vector_type(4)));

__device__ inline ushort f2bf(float v) {
  union { float f; unsigned u; } a; a.f = v;
  unsigned r = a.u + 0x7fffu + ((a.u >> 16) & 1u);
  return (ushort)(r >> 16);
}
__device__ inline float bf2f(ushort h) {
  union { unsigned u; float f; } a; a.u = ((unsigned)h) << 16;
  return a.f;
}

// ---------------- dtype detector: batch_indices int32 (stride 1) or int64 (stride 2)?
__global__ void detect_kernel(const int* __restrict__ idx32, int* __restrict__ flag) {
  __shared__ int s;
  int t = threadIdx.x;
  if (t == 0) s = 0;
  __syncthreads();
  int dec = 0;
  for (int i = t; i < 4095; i += 256)
    if (idx32[i + 1] < idx32[i]) dec = 1;
  if (dec) atomicOr(&s, 1);
  __syncthreads();
  if (t == 0) *flag = s ? 2 : 1;
}

// ---------------- segment starts from sorted indices
__global__ void bounds_kernel(const int* __restrict__ idx32, const int* __restrict__ flag,
                              int* __restrict__ starts, int n) {
  int st = *flag;
  int i = blockIdx.x * blockDim.x + threadIdx.x;
  if (i >= n) return;
  int cur = idx32[(size_t)i * st];
  int prev = (i == 0) ? -1 : idx32[(size_t)(i - 1) * st];
  if (cur != prev)
    for (int g = prev + 1; g <= cur; ++g) starts[g] = i;
  if (i == n - 1)
    for (int g = cur + 1; g <= NG; ++g) starts[g] = n;
}

// ---------------- weight prep: Wcat = W_ih + [W_hh | 0], split all weights into bf16 hi/lo
__global__ void wprep_kernel(const float* __restrict__ W_ih, const float* __restrict__ W_hh,
                             const float* __restrict__ b_ih, const float* __restrict__ b_hh,
                             const float* __restrict__ W1, const float* __restrict__ W2,
                             ushort* __restrict__ Wch, ushort* __restrict__ Wcl,
                             ushort* __restrict__ W1h, ushort* __restrict__ W1l,
                             ushort* __restrict__ W2h, ushort* __restrict__ W2l,
                             float* __restrict__ bcat) {
  int i = blockIdx.x * 256 + threadIdx.x;
  if (i < 524288) {
    int j = i >> 9, k = i & 511;
    float w = W_ih[i] + (k < 256 ? W_hh[j * 256 + k] : 0.f);
    ushort hi = f2bf(w);
    Wch[i] = hi; Wcl[i] = f2bf(w - bf2f(hi));
    if (i < 1024) bcat[i] = b_ih[i] + b_hh[i];
  } else if (i < 524288 + 131072) {
    int t = i - 524288;
    float w = W1[t];
    ushort hi = f2bf(w);
    W1h[t] = hi; W1l[t] = f2bf(w - bf2f(hi));
  } else if (i < 524288 + 131072 + 65536) {
    int t = i - 524288 - 131072;
    float w = W2[t];
    ushort hi = f2bf(w);
    W2h[t] = hi; W2l[t] = f2bf(w - bf2f(hi));
  }
}

// ---------------- zero h, c, and the h-half of xhi/xlo
__global__ __launch_bounds__(256) void init_kernel(float* __restrict__ h, float* __restrict__ c,
                                                   ushort* __restrict__ xhi, ushort* __restrict__ xlo) {
  int g = blockIdx.x, j = threadIdx.x;
  h[(size_t)g * 256 + j] = 0.f;
  c[(size_t)g * 256 + j] = 0.f;
  xhi[(size_t)g * 512 + j] = 0;
  xlo[(size_t)g * 512 + j] = 0;
}

// ---------------- fused attention: one block/graph, online softmax, 2 ILP chains per wave
__global__ __launch_bounds__(256) void attn_kernel(const float* __restrict__ emb,
                                                   const int* __restrict__ starts,
                                                   const float* __restrict__ h,
                                                   ushort* __restrict__ xhi,
                                                   ushort* __restrict__ xlo) {
  int g = blockIdx.x;
  int s = starts[g], e = starts[g + 1];
  int tid = threadIdx.x;
  if (s >= e) {
    xhi[(size_t)g * 512 + 256 + tid] = 0;
    xlo[(size_t)g * 512 + 256 + tid] = 0;
    return;
  }
  __shared__ float hs[256];
  __shared__ float redM[4], redS[4];
  __shared__ float redR[4][256];
  hs[tid] = h[(size_t)g * 256 + tid];
  __syncthreads();
  int wave = tid >> 6, lane = tid & 63;
  float4 h4 = *(const float4*)&hs[lane * 4];
  float M0 = -INFINITY, S0 = 0.f, M1 = -INFINITY, S1 = 0.f;
  float4 R0 = make_float4(0.f, 0.f, 0.f, 0.f), R1 = make_float4(0.f, 0.f, 0.f, 0.f);
  for (int n = s + wave * 2; n < e; n += 8) {
    const float* p0 = emb + (size_t)n * 256 + lane * 4;
    float4 v0 = *(const float4*)p0;
    bool has1 = (n + 1) < e;
    float4 v1 = make_float4(0.f, 0.f, 0.f, 0.f);
    if (has1) v1 = *(const float4*)(p0 + 256);
    float d0 = v0.x * h4.x + v0.y * h4.y + v0.z * h4.z + v0.w * h4.w;
    float d1 = v1.x * h4.x + v1.y * h4.y + v1.z * h4.z + v1.w * h4.w;
#pragma unroll
    for (int off = 32; off > 0; off >>= 1) {
      d0 += __shfl_xor(d0, off, 64);
      d1 += __shfl_xor(d1, off, 64);
    }
    if (d0 <= M0) {
      float w = __expf(d0 - M0);
      S0 += w;
      R0.x += w * v0.x; R0.y += w * v0.y; R0.z += w * v0.z; R0.w += w * v0.w;
    } else {
      float cc = __expf(M0 - d0);
      S0 = S0 * cc + 1.f;
      R0.x = R0.x * cc + v0.x; R0.y = R0.y * cc + v0.y;
      R0.z = R0.z * cc + v0.z; R0.w = R0.w * cc + v0.w;
      M0 = d0;
    }
    if (has1) {
      if (d1 <= M1) {
        float w = __expf(d1 - M1);
        S1 += w;
        R1.x += w * v1.x; R1.y += w * v1.y; R1.z += w * v1.z; R1.w += w * v1.w;
      } else {
        float cc = __expf(M1 - d1);
        S1 = S1 * cc + 1.f;
        R1.x = R1.x * cc + v1.x; R1.y = R1.y * cc + v1.y;
        R1.z = R1.z * cc + v1.z; R1.w = R1.w * cc + v1.w;
        M1 = d1;
      }
    }
  }
  if (M1 != -INFINITY) {  // merge chain1 into chain0 (M1 finite => M0 finite)
    float mm = fmaxf(M0, M1);
    float f0 = __expf(M0 - mm), f1 = __expf(M1 - mm);
    S0 = S0 * f0 + S1 * f1;
    R0.x = R0.x * f0 + R1.x * f1; R0.y = R0.y * f0 + R1.y * f1;
    R0.z = R0.z * f0 + R1.z * f1; R0.w = R0.w * f0 + R1.w * f1;
    M0 = mm;
  }
  if (lane == 0) { redM[wave] = M0; redS[wave] = S0; }
  *(float4*)&redR[wave][lane * 4] = R0;
  __syncthreads();
  float m = fmaxf(fmaxf(redM[0], redM[1]), fmaxf(redM[2], redM[3]));
  float St = 0.f, Rt = 0.f;
#pragma unroll
  for (int w = 0; w < 4; ++w) {
    float mw = redM[w];
    float f = (mw == -INFINITY) ? 0.f : __expf(mw - m);
    St += f * redS[w];
    Rt += f * redR[w][tid];
  }
  float rv = Rt / St;
  ushort hi = f2bf(rv);
  xhi[(size_t)g * 512 + 256 + tid] = hi;
  xlo[(size_t)g * 512 + 256 + tid] = f2bf(rv - bf2f(hi));
}

// ---------------- split-bf16 MFMA GEMM: C(M,N) = A(M,K) @ B(N,K)^T + bias
// A,B given as bf16 hi/lo pairs; C = Ahi*Bhi + Ahi*Blo + Alo*Bhi (fp32-class accuracy).
// 128x128 block tile, BK=32, 4 waves each computing 64x64 via 4x4 of 16x16x32 MFMA.
// mode: 0 = fp32 store; 1 = relu + fp32; 2 = relu + bf16 hi/lo split store.
#define AP 40  // LDS row pitch in shorts (32 + 8 pad -> 80B stride, 2-way banks = free)
__global__ __launch_bounds__(256) void gemm_mfma(
    const ushort* __restrict__ Ahi, const ushort* __restrict__ Alo,
    const ushort* __restrict__ Bhi, const ushort* __restrict__ Blo,
    const float* __restrict__ bias, float* __restrict__ Cf,
    ushort* __restrict__ Chi, ushort* __restrict__ Clo,
    int N, int K, int mode) {
  __shared__ ushort sAh[128 * AP], sAl[128 * AP], sBh[128 * AP], sBl[128 * AP];
  int tid = threadIdx.x;
  int wave = tid >> 6, lane = tid & 63;
  int fr = lane & 15, fq = lane >> 4;
  int wm = (wave >> 1) * 64, wn = (wave & 1) * 64;
  int r0 = blockIdx.y * 128, c0 = blockIdx.x * 128;
  int lr = tid >> 2, lk = (tid & 3) * 8;
  const ushort* pah = Ahi + (size_t)(r0 + lr) * K + lk;
  const ushort* pal = Alo + (size_t)(r0 + lr) * K + lk;
  const ushort* pbh = Bhi + (size_t)(c0 + lr) * K + lk;
  const ushort* pbl = Blo + (size_t)(c0 + lr) * K + lk;
  size_t rstr = (size_t)64 * K;
  int lo0 = lr * AP + lk, lo1 = (lr + 64) * AP + lk;
  f32x4 acc[4][4] = {};
  for (int k0 = 0; k0 < K; k0 += 32) {
    uint4 a0 = *(const uint4*)(pah + k0);
    uint4 a1 = *(const uint4*)(pah + rstr + k0);
    uint4 a2 = *(const uint4*)(pal + k0);
    uint4 a3 = *(const uint4*)(pal + rstr + k0);
    uint4 b0 = *(const uint4*)(pbh + k0);
    uint4 b1 = *(const uint4*)(pbh + rstr + k0);
    uint4 b2 = *(const uint4*)(pbl + k0);
    uint4 b3 = *(const uint4*)(pbl + rstr + k0);
    *(uint4*)&sAh[lo0] = a0; *(uint4*)&sAh[lo1] = a1;
    *(uint4*)&sAl[lo0] = a2; *(uint4*)&sAl[lo1] = a3;
    *(uint4*)&sBh[lo0] = b0; *(uint4*)&sBh[lo1] = b1;
    *(uint4*)&sBl[lo0] = b2; *(uint4*)&sBl[lo1] = b3;
    __syncthreads();
    bfrag ah[4], al[4], bh[4], bl[4];
#pragma unroll
    for (int t = 0; t < 4; ++t) {
      int ra = (wm + t * 16 + fr) * AP + fq * 8;
      int rb = (wn + t * 16 + fr) * AP + fq * 8;
      ah[t] = *(const bfrag*)&sAh[ra];
      al[t] = *(const bfrag*)&sAl[ra];
      bh[t] = *(const bfrag*)&sBh[rb];
      bl[t] = *(const bfrag*)&sBl[rb];
    }
#pragma unroll
    for (int mt = 0; mt < 4; ++mt)
#pragma unroll
      for (int nt = 0; nt < 4; ++nt) {
        acc[mt][nt] = __builtin_amdgcn_mfma_f32_16x16x32_bf16(ah[mt], bh[nt], acc[mt][nt], 0, 0, 0);
        acc[mt][nt] = __builtin_amdgcn_mfma_f32_16x16x32_bf16(ah[mt], bl[nt], acc[mt][nt], 0, 0, 0);
        acc[mt][nt] = __builtin_amdgcn_mfma_f32_16x16x32_bf16(al[mt], bh[nt], acc[mt][nt], 0, 0, 0);
      }
    __syncthreads();
  }
#pragma unroll
  for (int mt = 0; mt < 4; ++mt)
#pragma unroll
    for (int nt = 0; nt < 4; ++nt) {
      int n = c0 + wn + nt * 16 + fr;
      float bv = bias[n];
#pragma unroll
      for (int rg = 0; rg < 4; ++rg) {
        int m = r0 + wm + mt * 16 + fq * 4 + rg;
        float v = acc[mt][nt][rg] + bv;
        if (mode >= 1) v = fmaxf(v, 0.f);
        if (mode == 2) {
          ushort hi = f2bf(v);
          Chi[(size_t)m * N + n] = hi;
          Clo[(size_t)m * N + n] = f2bf(v - bf2f(hi));
        } else {
          Cf[(size_t)m * N + n] = v;
        }
      }
    }
}

// ---------------- LSTM elementwise: gates (G,1024) i,f,g,o; writes h fp32 + split x h-half
__global__ __launch_bounds__(256) void lstm_kernel(const float* __restrict__ gates,
                                                   float* __restrict__ c, float* __restrict__ h,
                                                   ushort* __restrict__ xhi, ushort* __restrict__ xlo) {
  int g = blockIdx.x, j = threadIdx.x;
  const float* gr = gates + (size_t)g * 1024;
  float gi = gr[j], gf = gr[j + 256], gg = gr[j + 512], go = gr[j + 768];
  float si = 1.f / (1.f + __expf(-gi));
  float sf = 1.f / (1.f + __expf(-gf));
  float so = 1.f / (1.f + __expf(-go));
  float tg = tanhf(gg);
  float cn = sf * c[(size_t)g * 256 + j] + si * tg;
  c[(size_t)g * 256 + j] = cn;
  float hn = so * tanhf(cn);
  h[(size_t)g * 256 + j] = hn;
  ushort hi = f2bf(hn);
  xhi[(size_t)g * 512 + j] = hi;
  xlo[(size_t)g * 512 + j] = f2bf(hn - bf2f(hi));
}

extern "C" void kernel_launch(void* const* d_in, const int* in_sizes, int n_in,
                              void* d_out, int out_size, void* d_ws, size_t ws_size,
                              hipStream_t stream) {
  const float* emb   = (const float*)d_in[0];
  const int*   idx32 = (const int*)d_in[1];
  const float* W_ih  = (const float*)d_in[2];
  const float* W_hh  = (const float*)d_in[3];
  const float* b_ih  = (const float*)d_in[4];
  const float* b_hh  = (const float*)d_in[5];
  const float* W1    = (const float*)d_in[6];
  const float* b1    = (const float*)d_in[7];
  const float* W2    = (const float*)d_in[8];
  const float* b2    = (const float*)d_in[9];
  float* out = (float*)d_out;
  int N = in_sizes[1];

  char* ws = (char*)d_ws;
  size_t o = 0;
  auto alloc = [&](size_t bytes) { void* p = ws + o; o = (o + bytes + 255) & ~(size_t)255; return p; };
  int*    flag  = (int*)alloc(4);
  int*    starts= (int*)alloc(((size_t)NG + 1) * 4);
  float*  bcat  = (float*)alloc(1024 * 4);
  ushort* Wch   = (ushort*)alloc((size_t)1024 * 512 * 2);
  ushort* Wcl   = (ushort*)alloc((size_t)1024 * 512 * 2);
  ushort* W1h   = (ushort*)alloc((size_t)256 * 512 * 2);
  ushort* W1l   = (ushort*)alloc((size_t)256 * 512 * 2);
  ushort* W2h   = (ushort*)alloc((size_t)256 * 256 * 2);
  ushort* W2l   = (ushort*)alloc((size_t)256 * 256 * 2);
  float*  h     = (float*)alloc((size_t)NG * 256 * 4);
  float*  c     = (float*)alloc((size_t)NG * 256 * 4);
  ushort* xhi   = (ushort*)alloc((size_t)NG * 512 * 2);
  ushort* xlo   = (ushort*)alloc((size_t)NG * 512 * 2);
  float*  gates = (float*)alloc((size_t)NG * 1024 * 4);
  ushort* hdnh  = (ushort*)alloc((size_t)NG * 256 * 2);
  ushort* hdnl  = (ushort*)alloc((size_t)NG * 256 * 2);

  detect_kernel<<<1, 256, 0, stream>>>(idx32, flag);
  bounds_kernel<<<(N + 255) / 256, 256, 0, stream>>>(idx32, flag, starts, N);
  wprep_kernel<<<(524288 + 131072 + 65536) / 256, 256, 0, stream>>>(
      W_ih, W_hh, b_ih, b_hh, W1, W2, Wch, Wcl, W1h, W1l, W2h, W2l, bcat);
  init_kernel<<<NG, 256, 0, stream>>>(h, c, xhi, xlo);

  for (int step = 0; step < 6; ++step) {
    attn_kernel<<<NG, 256, 0, stream>>>(emb, starts, h, xhi, xlo);
    gemm_mfma<<<dim3(1024 / 128, 4096 / 128), 256, 0, stream>>>(
        xhi, xlo, Wch, Wcl, bcat, gates, (ushort*)nullptr, (ushort*)nullptr, 1024, 512, 0);
    lstm_kernel<<<NG, 256, 0, stream>>>(gates, c, h, xhi, xlo);
  }

  gemm_mfma<<<dim3(256 / 128, 4096 / 128), 256, 0, stream>>>(
      xhi, xlo, W1h, W1l, b1, (float*)nullptr, hdnh, hdnl, 256, 512, 2);
  gemm_mfma<<<dim3(256 / 128, 4096 / 128), 256, 0, stream>>>(
      hdnh, hdnl, W2h, W2l, b2, out, (ushort*)nullptr, (ushort*)nullptr, 256, 256, 0);
}